// Round 7
// baseline (1191.496 us; speedup 1.0000x reference)
//
#include <hip/hip_runtime.h>
#include <cstdint>
#include <cstddef>

#define NEGV (-1e30f)

constexpr int C_ = 512, H_ = 128, W_ = 128;
constexpr int P_ = 16384;   // H*W

typedef short bf16x8 __attribute__((ext_vector_type(8)));
typedef float f32x4  __attribute__((ext_vector_type(4)));
#define MFMA16(a, b, c) __builtin_amdgcn_mfma_f32_16x16x32_bf16((a), (b), (c), 0, 0, 0)

// Swizzled LDS offsets (units: shorts). 16B slots XOR'd with row&7 so that
// stride-128B/256B column reads (ds_read_b128) spread across all banks.
// Rule #21: with global_load_lds the LDS dest is LINEAR (idx*16B) and the
// GLOBAL source slot is pre-XOR'd with the same involution; reads use SWZ*.
#define SWZ128(r, cs) (((r) << 7) + (((((cs) >> 3) ^ ((r) & 7))) << 3) + ((cs) & 7))
#define SWZ64(r, cs)  (((r) << 6) + (((((cs) >> 3) ^ ((r) & 7))) << 3) + ((cs) & 7))

__device__ inline void gl_lds16(const void* g, void* l) {
    __builtin_amdgcn_global_load_lds(
        (const __attribute__((address_space(1))) unsigned int*)g,
        (__attribute__((address_space(3))) unsigned int*)l, 16, 0, 0);
}

__device__ inline unsigned short f2bf(float f) {
    union { float f; uint32_t i; } t; t.f = f;
    uint32_t r = t.i + 0x7FFFu + ((t.i >> 16) & 1u);   // RNE
    return (unsigned short)(r >> 16);
}

// ---------------------------------------------------------------------------
// Weight conversion: Wq,Wk -> Wqkbf[128][512] (q rows 0..63, k rows 64..127);
// Wv -> Wvbf[512][512]. 4 elems/thread.
__global__ __launch_bounds__(256) void kwconv(
    const float* __restrict__ Wq, const float* __restrict__ Wk,
    const float* __restrict__ Wv,
    unsigned short* __restrict__ Wqkbf, unsigned short* __restrict__ Wvbf)
{
    const int i4 = (blockIdx.x * 256 + threadIdx.x) * 4;
    const float* src; unsigned short* dst; int off;
    if (i4 < 32768)       { src = Wq + i4;          dst = Wqkbf + i4; }
    else if (i4 < 65536)  { off = i4 - 32768; src = Wk + off; dst = Wqkbf + i4; }
    else                  { off = i4 - 65536; src = Wv + off; dst = Wvbf + off; }
    const float4 v = *(const float4*)src;
    ushort4 u; u.x = f2bf(v.x); u.y = f2bf(v.y); u.z = f2bf(v.z); u.w = f2bf(v.w);
    *(ushort4*)dst = u;
}

// ---------------------------------------------------------------------------
// x[b][c][h][w] fp32 -> xTbf[b][c][w][h] bf16 (per-map 128x128 transpose)
// plus optional straight-cast copy xbf[b][c][h][w] bf16 (for kagg2 DMA staging).
__global__ __launch_bounds__(256) void kprep1(
    const float* __restrict__ x, unsigned short* __restrict__ xTbf,
    unsigned short* __restrict__ xbf)
{
    __shared__ float t[32][33];
    const int tid = threadIdx.x;
    const int h0 = (blockIdx.x >> 2) * 32, w0 = (blockIdx.x & 3) * 32;
    const size_t base = (size_t)blockIdx.y * P_;
    {
        const int r = tid >> 3, c4 = (tid & 7) * 4;
        const float4 v = *(const float4*)&x[base + (size_t)(h0 + r) * 128 + w0 + c4];
        t[r][c4] = v.x; t[r][c4 + 1] = v.y; t[r][c4 + 2] = v.z; t[r][c4 + 3] = v.w;
        if (xbf) {
            ushort4 u; u.x = f2bf(v.x); u.y = f2bf(v.y); u.z = f2bf(v.z); u.w = f2bf(v.w);
            *(ushort4*)&xbf[base + (size_t)(h0 + r) * 128 + w0 + c4] = u;
        }
    }
    __syncthreads();
    {
        const int wr = tid >> 3, hc = (tid & 7) * 4;
        ushort4 u;
        u.x = f2bf(t[hc][wr]);     u.y = f2bf(t[hc + 1][wr]);
        u.z = f2bf(t[hc + 2][wr]); u.w = f2bf(t[hc + 3][wr]);
        *(ushort4*)&xTbf[base + (size_t)(w0 + wr) * 128 + h0 + hc] = u;
    }
}

// x[b][c][p] fp32 -> xbfT[b][p][c] bf16  (c <-> p transpose), tiles 32c x 32p
__global__ __launch_bounds__(256) void kprep2(
    const float* __restrict__ x, unsigned short* __restrict__ xbfT)
{
    __shared__ float t[32][33];
    const int tid = threadIdx.x;
    const int p0 = blockIdx.x * 32, c0 = blockIdx.y * 32, b = blockIdx.z;
    {
        const int r = tid >> 3, c4 = (tid & 7) * 4;     // r = c index, c4 = p index
        const float4 v = *(const float4*)&x[((size_t)(b * C_ + c0 + r)) * P_ + p0 + c4];
        t[r][c4] = v.x; t[r][c4 + 1] = v.y; t[r][c4 + 2] = v.z; t[r][c4 + 3] = v.w;
    }
    __syncthreads();
    {
        const int pr = tid >> 3, cc = (tid & 7) * 4;
        ushort4 u;
        u.x = f2bf(t[cc][pr]);     u.y = f2bf(t[cc + 1][pr]);
        u.z = f2bf(t[cc + 2][pr]); u.w = f2bf(t[cc + 3][pr]);
        *(ushort4*)&xbfT[((size_t)b * P_ + p0 + pr) * C_ + c0 + cc] = u;
    }
}

// ---------------------------------------------------------------------------
// QK projection GEMM, K=512, 2-deep pipelined (counted vmcnt, raw s_barrier).
// D[m][n=p] = sum_c A[m][c] * Bm[p][c]; A = Wqkbf [128][512]; Bm = xbfT.
// Store bf16 at qkP[b][p][mk].
__global__ __launch_bounds__(256) void kgemmqk(
    const unsigned short* __restrict__ A, const unsigned short* __restrict__ Bm,
    unsigned short* __restrict__ outbf)
{
    __shared__ __attribute__((aligned(16))) unsigned short sA[2][128 * 64];
    __shared__ __attribute__((aligned(16))) unsigned short sB[2][128 * 64];
    const int tid = threadIdx.x;
    const int pbase = blockIdx.x * 128, b = blockIdx.z;
    const int lane = tid & 63, wv = tid >> 6;
    const int m0 = (wv >> 1) * 64, p0 = (wv & 1) * 64;
    const int fr = lane & 15, fq = lane >> 4;

    f32x4 acc[4][4];
#pragma unroll
    for (int i = 0; i < 4; i++)
#pragma unroll
        for (int j = 0; j < 4; j++) acc[i][j] = (f32x4){0.f, 0.f, 0.f, 0.f};

    const size_t brow0 = ((size_t)b * P_ + pbase) * 512;

#define QK_STAGE(chunk, buf) {                                                  \
        const int kc_ = (chunk) * 64;                                           \
        _Pragma("unroll")                                                       \
        for (int rep = 0; rep < 4; rep++) {                                     \
            const int idx = rep * 256 + tid;                                    \
            const int r_ = idx >> 3, kgs = (idx & 7) ^ (r_ & 7);                \
            gl_lds16(&A[(size_t)r_ * 512 + kc_ + kgs * 8], &sA[buf][idx * 8]);  \
            gl_lds16(&Bm[brow0 + (size_t)r_ * 512 + kc_ + kgs * 8], &sB[buf][idx * 8]); \
        } }

    QK_STAGE(0, 0);
    int cur = 0;
    for (int chunk = 0; chunk < 8; ++chunk) {
        if (chunk < 7) {
            QK_STAGE(chunk + 1, cur ^ 1);
            asm volatile("s_waitcnt vmcnt(8)" ::: "memory");   // chunk's 8 landed
        } else {
            asm volatile("s_waitcnt vmcnt(0)" ::: "memory");
        }
        __builtin_amdgcn_s_barrier();
#pragma unroll
        for (int kk = 0; kk < 64; kk += 32) {
            bf16x8 af[4], bfv[4];
#pragma unroll
            for (int t = 0; t < 4; t++) af[t]  = *(const bf16x8*)&sA[cur][SWZ64(m0 + t * 16 + fr, kk + fq * 8)];
#pragma unroll
            for (int t = 0; t < 4; t++) bfv[t] = *(const bf16x8*)&sB[cur][SWZ64(p0 + t * 16 + fr, kk + fq * 8)];
#pragma unroll
            for (int i = 0; i < 4; i++)
#pragma unroll
                for (int j = 0; j < 4; j++)
                    acc[i][j] = MFMA16(af[i], bfv[j], acc[i][j]);
        }
        if (chunk < 7) __builtin_amdgcn_s_barrier();   // readers done before re-stage
        cur ^= 1;
    }
#undef QK_STAGE

    // qkP[b][p][mk] bf16, pack 4 consecutive mk (quad*4+r) per store
#pragma unroll
    for (int tj = 0; tj < 4; tj++) {
        const int p_g = pbase + p0 + tj * 16 + fr;
        const size_t rowo = ((size_t)b * P_ + p_g) * 128;
#pragma unroll
        for (int ti = 0; ti < 4; ti++) {
            const int mk = m0 + ti * 16 + fq * 4;
            ushort4 u;
            u.x = f2bf(acc[ti][tj][0]); u.y = f2bf(acc[ti][tj][1]);
            u.z = f2bf(acc[ti][tj][2]); u.w = f2bf(acc[ti][tj][3]);
            *(ushort4*)&outbf[rowo + mk] = u;
        }
    }
}

// ---------------------------------------------------------------------------
// Logits + per-row tile softmax partials, fused row/col via blockIdx.z.
// Per (b, s): E[i][j] = sum_{m<64} Q[m][i]*K[m][j]; per row i compute
// m_i = max_j E, s_i = sum_j exp(E - m_i); store P[i][j] = exp(E-m_i) bf16
// (unnormalized) and (m_i, s_i) scalars. Joint normalization is deferred to
// kcomb + kagg2 epilogue (exact: softmax = f * P with f from kcomb).
// mode 0 (row, -> PP=PR): p(i) = s*128 + i
// mode 1 (col, -> PP=PC): p(i) = i*128 + s, diag mask
__global__ __launch_bounds__(256) void klogitsP(
    const unsigned short* __restrict__ qkP,
    unsigned short* __restrict__ PR, unsigned short* __restrict__ PC,
    float* __restrict__ MR, float* __restrict__ SR,
    float* __restrict__ MC, float* __restrict__ SC)
{
    __shared__ __attribute__((aligned(16))) unsigned short sPM[128 * 136];
    __shared__ float red[2][128];
    const int tid = threadIdx.x;
    const int s = blockIdx.x, b = blockIdx.y, mode = blockIdx.z;
    const int rowMul  = mode ? 1 : 128;
    const int rowStep = mode ? 128 : 1;
    unsigned short* PP = mode ? PC : PR;
    float* Ma = mode ? MC : MR;
    float* Sa = mode ? SC : SR;
    const size_t qbase = (size_t)b * P_ * 128;
    const int rb = s * rowMul;
#pragma unroll
    for (int rep = 0; rep < 8; rep++) {
        const int idx = rep * 256 + tid;
        const int mkg = idx & 15, i = idx >> 4;
        *(uint4*)&sPM[i * 136 + mkg * 8] =
            *(const uint4*)&qkP[qbase + (size_t)(rb + i * rowStep) * 128 + mkg * 8];
    }
    __syncthreads();

    const int lane = tid & 63, wv = tid >> 6;
    const int i0 = (wv >> 1) * 64, j0 = (wv & 1) * 64;
    const int fr = lane & 15, fq = lane >> 4;
    const int jh = wv & 1;

    f32x4 acc[4][4];
#pragma unroll
    for (int i = 0; i < 4; i++)
#pragma unroll
        for (int j = 0; j < 4; j++) acc[i][j] = (f32x4){0.f, 0.f, 0.f, 0.f};

#pragma unroll
    for (int kk = 0; kk < 64; kk += 32) {
        bf16x8 af[4], bfv[4];
#pragma unroll
        for (int t = 0; t < 4; t++) af[t]  = *(const bf16x8*)&sPM[(i0 + t * 16 + fr) * 136 + kk + fq * 8];
#pragma unroll
        for (int t = 0; t < 4; t++) bfv[t] = *(const bf16x8*)&sPM[(j0 + t * 16 + fr) * 136 + 64 + kk + fq * 8];
#pragma unroll
        for (int i = 0; i < 4; i++)
#pragma unroll
            for (int j = 0; j < 4; j++)
                acc[i][j] = MFMA16(af[i], bfv[j], acc[i][j]);
    }

    // Phase A: per-row (i) max over this wave's j-half, combine halves via LDS
    float mrow[4][4];
#pragma unroll
    for (int ti = 0; ti < 4; ti++)
#pragma unroll
        for (int r = 0; r < 4; r++) {
            const int i_g = i0 + ti * 16 + fq * 4 + r;
            float mx = -3.0e38f;
#pragma unroll
            for (int tj = 0; tj < 4; tj++) {
                const int j_g = j0 + tj * 16 + fr;
                float v = acc[ti][tj][r];
                if (mode && i_g == j_g) v = NEGV;
                mx = fmaxf(mx, v);
            }
#pragma unroll
            for (int off = 8; off > 0; off >>= 1) mx = fmaxf(mx, __shfl_xor(mx, off));
            red[jh][i_g] = mx;   // 16 fr-lanes write same value (benign)
        }
    __syncthreads();
#pragma unroll
    for (int ti = 0; ti < 4; ti++)
#pragma unroll
        for (int r = 0; r < 4; r++) {
            const int i_g = i0 + ti * 16 + fq * 4 + r;
            mrow[ti][r] = fmaxf(red[0][i_g], red[1][i_g]);
        }

    // Phase B: exps, bf16 P store, per-half row sums
    float wsum[4][4];
    unsigned short* Pb = PP + ((size_t)(b * 128 + s)) * P_;
#pragma unroll
    for (int ti = 0; ti < 4; ti++)
#pragma unroll
        for (int r = 0; r < 4; r++) {
            const int i_g = i0 + ti * 16 + fq * 4 + r;
            const float m_ = mrow[ti][r];
            float ts = 0.f;
#pragma unroll
            for (int tj = 0; tj < 4; tj++) {
                const int j_g = j0 + tj * 16 + fr;
                float v = acc[ti][tj][r];
                if (mode && i_g == j_g) v = NEGV;
                const float e = __expf(v - m_);
                ts += e;
                Pb[(size_t)i_g * 128 + j_g] = f2bf(e);
            }
#pragma unroll
            for (int off = 8; off > 0; off >>= 1) ts += __shfl_xor(ts, off);
            wsum[ti][r] = ts;
        }
    __syncthreads();                     // phase-A reads of red done
#pragma unroll
    for (int ti = 0; ti < 4; ti++)
#pragma unroll
        for (int r = 0; r < 4; r++)
            red[jh][i0 + ti * 16 + fq * 4 + r] = wsum[ti][r];
    __syncthreads();
    if (fr == 0 && jh == 0) {
#pragma unroll
        for (int ti = 0; ti < 4; ti++)
#pragma unroll
            for (int r = 0; r < 4; r++) {
                const int i_g = i0 + ti * 16 + fq * 4 + r;
                const size_t o = (((size_t)b * 128 + s) << 7) + i_g;
                Ma[o] = mrow[ti][r];
                Sa[o] = red[0][i_g] + red[1][i_g];
            }
    }
}

// ---------------------------------------------------------------------------
// Joint-softmax combine: per pixel compute fR, fC such that the normalized
// attention rows are fR*PR and fC*PC. 1 thread/pixel.
__global__ __launch_bounds__(256) void kcomb(
    const float* __restrict__ MR, const float* __restrict__ SR,
    const float* __restrict__ MC, const float* __restrict__ SC,
    float* __restrict__ FR, float* __restrict__ FC)
{
    const int idx = blockIdx.x * 256 + threadIdx.x;
    const int b = idx >> 14, rem = idx & 16383;
    const int h = rem >> 7, w = rem & 127;
    const int ro = (b << 14) + (h << 7) + w;
    const int co = (b << 14) + (w << 7) + h;
    const float mR = MR[ro], sR = SR[ro];
    const float mC = MC[co], sC = SC[co];
    const float m = fmaxf(mR, mC);
    const float eR = __expf(mR - m), eC = __expf(mC - m);
    const float inv = 1.0f / (sR * eR + sC * eC);
    FR[ro] = eR * inv;
    FC[co] = eC * inv;
}

// ---------------------------------------------------------------------------
// Fused aggregation. Grid (s=128, b=4, mode=2), 256 threads.
// mode 0 (row): ySumR[b][p=s*128+i][c] = fR[p] * sum_j PR[b][s][i][j] * x[b][c][s*128+j]
// mode 1 (col): ySumC[b][p=i*128+s][c] = fC[p] * sum_j PC[b][s][i][j] * xTbf[b][c][s*128+j]
__global__ __launch_bounds__(256) void kagg2(
    const unsigned short* __restrict__ PR, const unsigned short* __restrict__ PC,
    const float* __restrict__ x, const unsigned short* __restrict__ xbf,
    const unsigned short* __restrict__ xTbf,
    const float* __restrict__ FR, const float* __restrict__ FC,
    unsigned short* __restrict__ ySumR, unsigned short* __restrict__ ySumC)
{
    __shared__ __attribute__((aligned(16))) unsigned short sAttn[128 * 128];
    __shared__ __attribute__((aligned(16))) unsigned short sX[128 * 128];
    __shared__ float sF[128];
    const int tid = threadIdx.x;
    const int s = blockIdx.x, b = blockIdx.y, mode = blockIdx.z;
    const int lane = tid & 63, wv = tid >> 6;
    const int m0 = (wv >> 1) * 64, n0 = (wv & 1) * 64;   // m = c tile, n = i tile
    const int fr = lane & 15, fq = lane >> 4;

    // stage attention tile 128x128 once: linear LDS dest, inverse-swizzled src
    const unsigned short* At = (mode ? PC : PR) + ((size_t)(b * 128 + s)) * P_;
#pragma unroll
    for (int rep = 0; rep < 8; rep++) {
        const int idx = rep * 256 + tid;
        const int r = idx >> 4, sl = idx & 15;
        gl_lds16(&At[(size_t)r * 128 + (sl ^ (r & 7)) * 8], &sAttn[idx * 8]);
    }
    // stage per-row scale factors (contiguous 128 floats for this block)
    const float* Fsel = mode ? FC : FR;
    if (tid < 128) sF[tid] = Fsel[(((size_t)b * 128 + s) << 7) + tid];

    unsigned short* yS = mode ? ySumC : ySumR;
    const unsigned short* Xsrc = mode ? xTbf : xbf;

    for (int ct = 0; ct < 4; ct++) {
        if (Xsrc) {
            const unsigned short* Xs = &Xsrc[((size_t)(b * C_ + ct * 128)) * P_ + s * 128];
#pragma unroll
            for (int rep = 0; rep < 8; rep++) {
                const int idx = rep * 256 + tid;
                const int r = idx >> 4, sl = idx & 15;
                gl_lds16(&Xs[(size_t)r * P_ + (sl ^ (r & 7)) * 8], &sX[idx * 8]);
            }
        } else {
            const float* Xf = &x[((size_t)(b * C_ + ct * 128)) * P_ + s * 128];
#pragma unroll
            for (int rep = 0; rep < 16; rep++) {
                const int idx = rep * 256 + tid;
                const int jq = idx & 31, cc = idx >> 5;
                const float4 v = *(const float4*)&Xf[(size_t)cc * P_ + jq * 4];
                ushort4 u; u.x = f2bf(v.x); u.y = f2bf(v.y); u.z = f2bf(v.z); u.w = f2bf(v.w);
                *(ushort4*)&sX[SWZ128(cc, jq * 4)] = u;
            }
        }
        __syncthreads();

        f32x4 acc[4][4];
#pragma unroll
        for (int i = 0; i < 4; i++)
#pragma unroll
            for (int j = 0; j < 4; j++) acc[i][j] = (f32x4){0.f, 0.f, 0.f, 0.f};

#pragma unroll
        for (int kk = 0; kk < 128; kk += 32) {
            bf16x8 af[4], bfv[4];
#pragma unroll
            for (int t = 0; t < 4; t++) {
                const int rc = m0 + t * 16 + fr;
                af[t] = *(const bf16x8*)&sX[SWZ128(rc, kk + fq * 8)];
            }
#pragma unroll
            for (int t = 0; t < 4; t++) {
                const int ri = n0 + t * 16 + fr;
                bfv[t] = *(const bf16x8*)&sAttn[SWZ128(ri, kk + fq * 8)];
            }
#pragma unroll
            for (int i = 0; i < 4; i++)
#pragma unroll
                for (int j = 0; j < 4; j++)
                    acc[i][j] = MFMA16(af[i], bfv[j], acc[i][j]);
        }

        // epilogue: lane holds c = cg0 + ti*16 + {0..3}, i = n0 + tj*16 + fr
        const int cg0 = ct * 128 + m0 + fq * 4;
#pragma unroll
        for (int tj = 0; tj < 4; tj++) {
            const int i_g = n0 + tj * 16 + fr;
            const float fsc = sF[i_g];
            const size_t p = mode ? ((size_t)i_g * 128 + s) : ((size_t)s * 128 + i_g);
            unsigned short* rowp = yS + ((size_t)b * P_ + p) * 512;
#pragma unroll
            for (int ti = 0; ti < 4; ti++) {
                ushort4 u;
                u.x = f2bf(acc[ti][tj][0] * fsc); u.y = f2bf(acc[ti][tj][1] * fsc);
                u.z = f2bf(acc[ti][tj][2] * fsc); u.w = f2bf(acc[ti][tj][3] * fsc);
                *(ushort4*)&rowp[cg0 + ti * 16] = u;
            }
        }
        __syncthreads();   // all waves done reading sX before next ct overwrites it
    }
}

// ---------------------------------------------------------------------------
// Final GEMM, 256x256 tile, K=1024 concat, SINGLE-buffered (64 KB LDS ->
// 2 blocks/CU): stage chunk -> sync -> compute -> sync. Cross-block TLP
// (m114) overlaps one block's stage with the other's MFMA phase, while
// keeping the 256^2 tile's halved traffic (8 MFMA/KB staged, mt=2).
// 512 threads / 8 waves (2m x 4p); per-wave output 128m x 64p — fragment
// math and epilogue identical to the verified r4 kernel.
__global__ __launch_bounds__(512, 4) void kfinalS(
    const unsigned short* __restrict__ Wvbf,
    const unsigned short* __restrict__ yR,
    const unsigned short* __restrict__ yC,
    float* __restrict__ outf,
    const float* __restrict__ addx,
    const float* __restrict__ gammap)
{
    __shared__ __attribute__((aligned(16))) unsigned short sM[256 * 64]; // Wv rows (m)
    __shared__ __attribute__((aligned(16))) unsigned short sP[256 * 64]; // ySum rows (p)
    const int tid = threadIdx.x;
    const int pbase = blockIdx.x * 256, mt = blockIdx.y, b = blockIdx.z;
    const int lane = tid & 63, wv = tid >> 6;
    const int m0w = (wv >> 2) * 128;   // 2 m-groups of 128
    const int p0w = (wv & 3) * 64;     // 4 p-groups of 64
    const int fr = lane & 15, fq = lane >> 4;

    f32x4 acc[4][8];
#pragma unroll
    for (int i = 0; i < 4; i++)
#pragma unroll
        for (int j = 0; j < 8; j++) acc[i][j] = (f32x4){0.f, 0.f, 0.f, 0.f};

    const unsigned short* Arow = Wvbf + (size_t)(mt * 256) * 512;
    const size_t brow = ((size_t)b * P_ + pbase) * 512;

    for (int chunk = 0; chunk < 16; ++chunk) {
        const int kc = (chunk & 7) * 64;
        const unsigned short* Bp = (chunk < 8 ? yR : yC) + brow + kc;
        const unsigned short* Ap = Arow + kc;
        // stage 256x64 A + 256x64 B (linear LDS dest, inverse-swizzled src)
#pragma unroll
        for (int rep = 0; rep < 4; rep++) {
            const int idx = rep * 512 + tid;
            const int r_ = idx >> 3, kgs = (idx & 7) ^ (r_ & 7);
            gl_lds16(&Ap[(size_t)r_ * 512 + kgs * 8], &sM[idx * 8]);
            gl_lds16(&Bp[(size_t)r_ * 512 + kgs * 8], &sP[idx * 8]);
        }
        __syncthreads();   // drains vmcnt: tiles ready
#pragma unroll
        for (int kk = 0; kk < 64; kk += 32) {
            bf16x8 bp[4], am[8];
#pragma unroll
            for (int t = 0; t < 4; t++) bp[t] = *(const bf16x8*)&sP[SWZ64(p0w + t * 16 + fr, kk + fq * 8)];
#pragma unroll
            for (int t = 0; t < 8; t++) am[t] = *(const bf16x8*)&sM[SWZ64(m0w + t * 16 + fr, kk + fq * 8)];
            __builtin_amdgcn_s_setprio(1);
#pragma unroll
            for (int i = 0; i < 4; i++)
#pragma unroll
                for (int j = 0; j < 8; j++)
                    acc[i][j] = MFMA16(bp[i], am[j], acc[i][j]);
            __builtin_amdgcn_s_setprio(0);
        }
        __syncthreads();   // all waves done reading before next stage overwrites
    }

    // epilogue: lane's 4 regs = 4 consecutive p; float4 RMW against addx
    const float g = gammap[0];
#pragma unroll
    for (int ti = 0; ti < 4; ti++) {
        const int p_g = pbase + p0w + ti * 16 + fq * 4;
#pragma unroll
        for (int tj = 0; tj < 8; tj++) {
            const int m_g = mt * 256 + m0w + tj * 16 + fr;
            const size_t off = ((size_t)(b * 512 + m_g)) * P_ + p_g;
            const float4 xa = *(const float4*)&addx[off];
            float4 o;
            o.x = fmaf(g, acc[ti][tj][0], xa.x);
            o.y = fmaf(g, acc[ti][tj][1], xa.y);
            o.z = fmaf(g, acc[ti][tj][2], xa.z);
            o.w = fmaf(g, acc[ti][tj][3], xa.w);
            *(float4*)&outf[off] = o;
        }
    }
}

// ---------------------------------------------------------------------------
extern "C" void kernel_launch(void* const* d_in, const int* in_sizes, int n_in,
                              void* d_out, int out_size, void* d_ws, size_t ws_size,
                              hipStream_t stream) {
    const float* x     = (const float*)d_in[0];
    const float* Wq    = (const float*)d_in[1];
    const float* Wk    = (const float*)d_in[2];
    const float* Wv    = (const float*)d_in[3];
    const float* gamma = (const float*)d_in[4];
    float* out = (float*)d_out;

    char* base = (char*)d_ws;
    unsigned short* Wqkbf = (unsigned short*)base;             base += 131072;      // 128x512
    unsigned short* Wvbf  = (unsigned short*)base;             base += 524288;      // 512x512
    unsigned short* xTbf  = (unsigned short*)base;             base += 67108864;    // [b][c][w][h]
    unsigned short* xbfT  = (unsigned short*)base;             base += 67108864;    // [b][p][c]
    unsigned short* qkP   = (unsigned short*)base;             base += 16777216;    // [b][p][mk]
    char*           freeRC = base;                             base += 67108864;    // scratch: ySumC lives here
    unsigned short* PR    = (unsigned short*)base;             base += 16777216;    // [b][h][w][j] bf16 (unnormalized)
    unsigned short* PC    = (unsigned short*)base;             base += 16777216;    // [b][w][h][j]
    unsigned short* ySumR = (unsigned short*)base;             base += 67108864;    // [b][p][c]
    float*          MR    = (float*)base;                      base += 262144;      // [b][h][w]
    float*          SR    = (float*)base;                      base += 262144;
    float*          MC    = (float*)base;                      base += 262144;      // [b][w][h]
    float*          SC    = (float*)base;                      base += 262144;
    float*          FR    = (float*)base;                      base += 262144;
    float*          FC    = (float*)base;                      base += 262144;
    unsigned short* ySumC = (unsigned short*)freeRC;
    // xbf [b][c][p] bf16 straight-cast copy (64 MiB) — only if workspace allows
    const size_t used = (size_t)(base - (char*)d_ws);
    unsigned short* xbf = nullptr;
    if (ws_size >= used + 67108864) { xbf = (unsigned short*)base; base += 67108864; }

    kwconv<<<320, 256, 0, stream>>>(Wq, Wk, Wv, Wqkbf, Wvbf);
    kprep1<<<dim3(16, 2048), 256, 0, stream>>>(x, xTbf, xbf);
    kprep2<<<dim3(512, 16, 4), 256, 0, stream>>>(x, xbfT);
    // qk[b][p][mk] = Wqk @ x
    kgemmqk<<<dim3(128, 1, 4), 256, 0, stream>>>(Wqkbf, xbfT, qkP);
    // row (eW) + col (eH, diag-masked) logits -> unnormalized P + (m,s) scalars
    klogitsP<<<dim3(128, 4, 2), 256, 0, stream>>>(qkP, PR, PC, MR, SR, MC, SC);
    // joint-softmax scale factors
    kcomb<<<256, 256, 0, stream>>>(MR, SR, MC, SC, FR, FC);
    // fused row+col aggregation (scale folded into epilogue) -> ySumR / ySumC
    kagg2<<<dim3(128, 4, 2), 256, 0, stream>>>(PR, PC, x, xbf, xTbf, FR, FC, ySumR, ySumC);
    // out = gamma * Wv @ [ySumR | ySumC] + x, 256^2 single-buffered tiles
    kfinalS<<<dim3(64, 2, 4), 512, 0, stream>>>(Wvbf, ySumR, ySumC, out, x, gamma);
}

// Round 8
// 524.563 us; speedup vs baseline: 2.2714x; 2.2714x over previous
//
#include <hip/hip_runtime.h>
#include <cstdint>
#include <cstddef>

#define NEGV (-1e30f)

constexpr int C_ = 512, H_ = 128, W_ = 128;
constexpr int P_ = 16384;   // H*W

typedef short bf16x8 __attribute__((ext_vector_type(8)));
typedef float f32x4  __attribute__((ext_vector_type(4)));
#define MFMA16(a, b, c) __builtin_amdgcn_mfma_f32_16x16x32_bf16((a), (b), (c), 0, 0, 0)

// Swizzled LDS offsets (units: shorts). 16B slots XOR'd with row&7 so that
// stride-128B/256B column reads (ds_read_b128) spread across all banks.
// Rule #21: with global_load_lds the LDS dest is LINEAR (idx*16B) and the
// GLOBAL source slot is pre-XOR'd with the same involution; reads use SWZ*.
#define SWZ128(r, cs) (((r) << 7) + (((((cs) >> 3) ^ ((r) & 7))) << 3) + ((cs) & 7))
#define SWZ64(r, cs)  (((r) << 6) + (((((cs) >> 3) ^ ((r) & 7))) << 3) + ((cs) & 7))

__device__ inline void gl_lds16(const void* g, void* l) {
    __builtin_amdgcn_global_load_lds(
        (const __attribute__((address_space(1))) unsigned int*)g,
        (__attribute__((address_space(3))) unsigned int*)l, 16, 0, 0);
}

__device__ inline unsigned short f2bf(float f) {
    union { float f; uint32_t i; } t; t.f = f;
    uint32_t r = t.i + 0x7FFFu + ((t.i >> 16) & 1u);   // RNE
    return (unsigned short)(r >> 16);
}

// ---------------------------------------------------------------------------
// Weight conversion: Wq,Wk -> Wqkbf[128][512] (q rows 0..63, k rows 64..127);
// Wv -> Wvbf[512][512]. 4 elems/thread.
__global__ __launch_bounds__(256) void kwconv(
    const float* __restrict__ Wq, const float* __restrict__ Wk,
    const float* __restrict__ Wv,
    unsigned short* __restrict__ Wqkbf, unsigned short* __restrict__ Wvbf)
{
    const int i4 = (blockIdx.x * 256 + threadIdx.x) * 4;
    const float* src; unsigned short* dst; int off;
    if (i4 < 32768)       { src = Wq + i4;          dst = Wqkbf + i4; }
    else if (i4 < 65536)  { off = i4 - 32768; src = Wk + off; dst = Wqkbf + i4; }
    else                  { off = i4 - 65536; src = Wv + off; dst = Wvbf + off; }
    const float4 v = *(const float4*)src;
    ushort4 u; u.x = f2bf(v.x); u.y = f2bf(v.y); u.z = f2bf(v.z); u.w = f2bf(v.w);
    *(ushort4*)dst = u;
}

// ---------------------------------------------------------------------------
// x[b][c][h][w] fp32 -> xTbf[b][c][w][h] bf16 (per-map 128x128 transpose)
// plus optional straight-cast copy xbf[b][c][h][w] bf16 (feeds kprep2 + kagg2).
__global__ __launch_bounds__(256) void kprep1(
    const float* __restrict__ x, unsigned short* __restrict__ xTbf,
    unsigned short* __restrict__ xbf)
{
    __shared__ float t[32][33];
    const int tid = threadIdx.x;
    const int h0 = (blockIdx.x >> 2) * 32, w0 = (blockIdx.x & 3) * 32;
    const size_t base = (size_t)blockIdx.y * P_;
    {
        const int r = tid >> 3, c4 = (tid & 7) * 4;
        const float4 v = *(const float4*)&x[base + (size_t)(h0 + r) * 128 + w0 + c4];
        t[r][c4] = v.x; t[r][c4 + 1] = v.y; t[r][c4 + 2] = v.z; t[r][c4 + 3] = v.w;
        if (xbf) {
            ushort4 u; u.x = f2bf(v.x); u.y = f2bf(v.y); u.z = f2bf(v.z); u.w = f2bf(v.w);
            *(ushort4*)&xbf[base + (size_t)(h0 + r) * 128 + w0 + c4] = u;
        }
    }
    __syncthreads();
    {
        const int wr = tid >> 3, hc = (tid & 7) * 4;
        ushort4 u;
        u.x = f2bf(t[hc][wr]);     u.y = f2bf(t[hc + 1][wr]);
        u.z = f2bf(t[hc + 2][wr]); u.w = f2bf(t[hc + 3][wr]);
        *(ushort4*)&xTbf[base + (size_t)(w0 + wr) * 128 + h0 + hc] = u;
    }
}

// x -> xbfT[b][p][c] bf16 (c <-> p transpose), tiles 32c x 32p.
// If xbf != null reads the bf16 copy (half the traffic, bit-identical values
// since xbf is already the once-rounded f2bf(x)); else falls back to fp32 x.
__global__ __launch_bounds__(256) void kprep2(
    const float* __restrict__ x, const unsigned short* __restrict__ xbf,
    unsigned short* __restrict__ xbfT)
{
    __shared__ float tf[32][33];
    __shared__ unsigned short tb[32][34];
    const int tid = threadIdx.x;
    const int p0 = blockIdx.x * 32, c0 = blockIdx.y * 32, b = blockIdx.z;
    const int r = tid >> 3, c4 = (tid & 7) * 4;     // r = c index, c4 = p index
    if (xbf) {
        const ushort4 v = *(const ushort4*)&xbf[((size_t)(b * C_ + c0 + r)) * P_ + p0 + c4];
        tb[r][c4] = v.x; tb[r][c4 + 1] = v.y; tb[r][c4 + 2] = v.z; tb[r][c4 + 3] = v.w;
        __syncthreads();
        const int pr = tid >> 3, cc = (tid & 7) * 4;
        ushort4 u;
        u.x = tb[cc][pr];     u.y = tb[cc + 1][pr];
        u.z = tb[cc + 2][pr]; u.w = tb[cc + 3][pr];
        *(ushort4*)&xbfT[((size_t)b * P_ + p0 + pr) * C_ + c0 + cc] = u;
    } else {
        const float4 v = *(const float4*)&x[((size_t)(b * C_ + c0 + r)) * P_ + p0 + c4];
        tf[r][c4] = v.x; tf[r][c4 + 1] = v.y; tf[r][c4 + 2] = v.z; tf[r][c4 + 3] = v.w;
        __syncthreads();
        const int pr = tid >> 3, cc = (tid & 7) * 4;
        ushort4 u;
        u.x = f2bf(tf[cc][pr]);     u.y = f2bf(tf[cc + 1][pr]);
        u.z = f2bf(tf[cc + 2][pr]); u.w = f2bf(tf[cc + 3][pr]);
        *(ushort4*)&xbfT[((size_t)b * P_ + p0 + pr) * C_ + c0 + cc] = u;
    }
}

// ---------------------------------------------------------------------------
// QK projection GEMM, K=512, 2-deep pipelined (counted vmcnt, raw s_barrier).
// D[m][n=p] = sum_c A[m][c] * Bm[p][c]; A = Wqkbf [128][512]; Bm = xbfT.
// Store bf16 at qkP[b][p][mk].
__global__ __launch_bounds__(256) void kgemmqk(
    const unsigned short* __restrict__ A, const unsigned short* __restrict__ Bm,
    unsigned short* __restrict__ outbf)
{
    __shared__ __attribute__((aligned(16))) unsigned short sA[2][128 * 64];
    __shared__ __attribute__((aligned(16))) unsigned short sB[2][128 * 64];
    const int tid = threadIdx.x;
    const int pbase = blockIdx.x * 128, b = blockIdx.z;
    const int lane = tid & 63, wv = tid >> 6;
    const int m0 = (wv >> 1) * 64, p0 = (wv & 1) * 64;
    const int fr = lane & 15, fq = lane >> 4;

    f32x4 acc[4][4];
#pragma unroll
    for (int i = 0; i < 4; i++)
#pragma unroll
        for (int j = 0; j < 4; j++) acc[i][j] = (f32x4){0.f, 0.f, 0.f, 0.f};

    const size_t brow0 = ((size_t)b * P_ + pbase) * 512;

#define QK_STAGE(chunk, buf) {                                                  \
        const int kc_ = (chunk) * 64;                                           \
        _Pragma("unroll")                                                       \
        for (int rep = 0; rep < 4; rep++) {                                     \
            const int idx = rep * 256 + tid;                                    \
            const int r_ = idx >> 3, kgs = (idx & 7) ^ (r_ & 7);                \
            gl_lds16(&A[(size_t)r_ * 512 + kc_ + kgs * 8], &sA[buf][idx * 8]);  \
            gl_lds16(&Bm[brow0 + (size_t)r_ * 512 + kc_ + kgs * 8], &sB[buf][idx * 8]); \
        } }

    QK_STAGE(0, 0);
    int cur = 0;
    for (int chunk = 0; chunk < 8; ++chunk) {
        if (chunk < 7) {
            QK_STAGE(chunk + 1, cur ^ 1);
            asm volatile("s_waitcnt vmcnt(8)" ::: "memory");   // chunk's 8 landed
        } else {
            asm volatile("s_waitcnt vmcnt(0)" ::: "memory");
        }
        __builtin_amdgcn_s_barrier();
#pragma unroll
        for (int kk = 0; kk < 64; kk += 32) {
            bf16x8 af[4], bfv[4];
#pragma unroll
            for (int t = 0; t < 4; t++) af[t]  = *(const bf16x8*)&sA[cur][SWZ64(m0 + t * 16 + fr, kk + fq * 8)];
#pragma unroll
            for (int t = 0; t < 4; t++) bfv[t] = *(const bf16x8*)&sB[cur][SWZ64(p0 + t * 16 + fr, kk + fq * 8)];
#pragma unroll
            for (int i = 0; i < 4; i++)
#pragma unroll
                for (int j = 0; j < 4; j++)
                    acc[i][j] = MFMA16(af[i], bfv[j], acc[i][j]);
        }
        if (chunk < 7) __builtin_amdgcn_s_barrier();   // readers done before re-stage
        cur ^= 1;
    }
#undef QK_STAGE

    // qkP[b][p][mk] bf16, pack 4 consecutive mk (quad*4+r) per store
#pragma unroll
    for (int tj = 0; tj < 4; tj++) {
        const int p_g = pbase + p0 + tj * 16 + fr;
        const size_t rowo = ((size_t)b * P_ + p_g) * 128;
#pragma unroll
        for (int ti = 0; ti < 4; ti++) {
            const int mk = m0 + ti * 16 + fq * 4;
            ushort4 u;
            u.x = f2bf(acc[ti][tj][0]); u.y = f2bf(acc[ti][tj][1]);
            u.z = f2bf(acc[ti][tj][2]); u.w = f2bf(acc[ti][tj][3]);
            *(ushort4*)&outbf[rowo + mk] = u;
        }
    }
}

// ---------------------------------------------------------------------------
// Logits + per-row tile softmax partials, fused row/col via blockIdx.z.
// Per (b, s): E[i][j] = sum_{m<64} Q[m][i]*K[m][j]; per row i compute
// m_i = max_j E, s_i = sum_j exp(E - m_i); store P[i][j] = exp(E-m_i) bf16
// (unnormalized) and (m_i, s_i) scalars. Joint normalization is deferred to
// kcomb + kagg2 epilogue (exact: softmax = f * P with f from kcomb).
// mode 0 (row, -> PP=PR): p(i) = s*128 + i
// mode 1 (col, -> PP=PC): p(i) = i*128 + s, diag mask
__global__ __launch_bounds__(256) void klogitsP(
    const unsigned short* __restrict__ qkP,
    unsigned short* __restrict__ PR, unsigned short* __restrict__ PC,
    float* __restrict__ MR, float* __restrict__ SR,
    float* __restrict__ MC, float* __restrict__ SC)
{
    __shared__ __attribute__((aligned(16))) unsigned short sPM[128 * 136];
    __shared__ float red[2][128];
    const int tid = threadIdx.x;
    const int s = blockIdx.x, b = blockIdx.y, mode = blockIdx.z;
    const int rowMul  = mode ? 1 : 128;
    const int rowStep = mode ? 128 : 1;
    unsigned short* PP = mode ? PC : PR;
    float* Ma = mode ? MC : MR;
    float* Sa = mode ? SC : SR;
    const size_t qbase = (size_t)b * P_ * 128;
    const int rb = s * rowMul;
#pragma unroll
    for (int rep = 0; rep < 8; rep++) {
        const int idx = rep * 256 + tid;
        const int mkg = idx & 15, i = idx >> 4;
        *(uint4*)&sPM[i * 136 + mkg * 8] =
            *(const uint4*)&qkP[qbase + (size_t)(rb + i * rowStep) * 128 + mkg * 8];
    }
    __syncthreads();

    const int lane = tid & 63, wv = tid >> 6;
    const int i0 = (wv >> 1) * 64, j0 = (wv & 1) * 64;
    const int fr = lane & 15, fq = lane >> 4;
    const int jh = wv & 1;

    f32x4 acc[4][4];
#pragma unroll
    for (int i = 0; i < 4; i++)
#pragma unroll
        for (int j = 0; j < 4; j++) acc[i][j] = (f32x4){0.f, 0.f, 0.f, 0.f};

#pragma unroll
    for (int kk = 0; kk < 64; kk += 32) {
        bf16x8 af[4], bfv[4];
#pragma unroll
        for (int t = 0; t < 4; t++) af[t]  = *(const bf16x8*)&sPM[(i0 + t * 16 + fr) * 136 + kk + fq * 8];
#pragma unroll
        for (int t = 0; t < 4; t++) bfv[t] = *(const bf16x8*)&sPM[(j0 + t * 16 + fr) * 136 + 64 + kk + fq * 8];
#pragma unroll
        for (int i = 0; i < 4; i++)
#pragma unroll
            for (int j = 0; j < 4; j++)
                acc[i][j] = MFMA16(af[i], bfv[j], acc[i][j]);
    }

    // Phase A: per-row (i) max over this wave's j-half, combine halves via LDS
    float mrow[4][4];
#pragma unroll
    for (int ti = 0; ti < 4; ti++)
#pragma unroll
        for (int r = 0; r < 4; r++) {
            const int i_g = i0 + ti * 16 + fq * 4 + r;
            float mx = -3.0e38f;
#pragma unroll
            for (int tj = 0; tj < 4; tj++) {
                const int j_g = j0 + tj * 16 + fr;
                float v = acc[ti][tj][r];
                if (mode && i_g == j_g) v = NEGV;
                mx = fmaxf(mx, v);
            }
#pragma unroll
            for (int off = 8; off > 0; off >>= 1) mx = fmaxf(mx, __shfl_xor(mx, off));
            red[jh][i_g] = mx;   // 16 fr-lanes write same value (benign)
        }
    __syncthreads();
#pragma unroll
    for (int ti = 0; ti < 4; ti++)
#pragma unroll
        for (int r = 0; r < 4; r++) {
            const int i_g = i0 + ti * 16 + fq * 4 + r;
            mrow[ti][r] = fmaxf(red[0][i_g], red[1][i_g]);
        }

    // Phase B: exps, bf16 P store, per-half row sums
    float wsum[4][4];
    unsigned short* Pb = PP + ((size_t)(b * 128 + s)) * P_;
#pragma unroll
    for (int ti = 0; ti < 4; ti++)
#pragma unroll
        for (int r = 0; r < 4; r++) {
            const int i_g = i0 + ti * 16 + fq * 4 + r;
            const float m_ = mrow[ti][r];
            float ts = 0.f;
#pragma unroll
            for (int tj = 0; tj < 4; tj++) {
                const int j_g = j0 + tj * 16 + fr;
                float v = acc[ti][tj][r];
                if (mode && i_g == j_g) v = NEGV;
                const float e = __expf(v - m_);
                ts += e;
                Pb[(size_t)i_g * 128 + j_g] = f2bf(e);
            }
#pragma unroll
            for (int off = 8; off > 0; off >>= 1) ts += __shfl_xor(ts, off);
            wsum[ti][r] = ts;
        }
    __syncthreads();                     // phase-A reads of red done
#pragma unroll
    for (int ti = 0; ti < 4; ti++)
#pragma unroll
        for (int r = 0; r < 4; r++)
            red[jh][i0 + ti * 16 + fq * 4 + r] = wsum[ti][r];
    __syncthreads();
    if (fr == 0 && jh == 0) {
#pragma unroll
        for (int ti = 0; ti < 4; ti++)
#pragma unroll
            for (int r = 0; r < 4; r++) {
                const int i_g = i0 + ti * 16 + fq * 4 + r;
                const size_t o = (((size_t)b * 128 + s) << 7) + i_g;
                Ma[o] = mrow[ti][r];
                Sa[o] = red[0][i_g] + red[1][i_g];
            }
    }
}

// ---------------------------------------------------------------------------
// Joint-softmax combine: per pixel compute fR, fC such that the normalized
// attention rows are fR*PR and fC*PC. 1 thread/pixel.
__global__ __launch_bounds__(256) void kcomb(
    const float* __restrict__ MR, const float* __restrict__ SR,
    const float* __restrict__ MC, const float* __restrict__ SC,
    float* __restrict__ FR, float* __restrict__ FC)
{
    const int idx = blockIdx.x * 256 + threadIdx.x;
    const int b = idx >> 14, rem = idx & 16383;
    const int h = rem >> 7, w = rem & 127;
    const int ro = (b << 14) + (h << 7) + w;
    const int co = (b << 14) + (w << 7) + h;
    const float mR = MR[ro], sR = SR[ro];
    const float mC = MC[co], sC = SC[co];
    const float m = fmaxf(mR, mC);
    const float eR = __expf(mR - m), eC = __expf(mC - m);
    const float inv = 1.0f / (sR * eR + sC * eC);
    FR[ro] = eR * inv;
    FC[co] = eC * inv;
}

// ---------------------------------------------------------------------------
// Fused aggregation. Grid (s=128, b=4, mode=2), 256 threads.
// mode 0 (row): ySumR[b][p=s*128+i][c] = fR[p] * sum_j PR[b][s][i][j] * x[b][c][s*128+j]
// mode 1 (col): ySumC[b][p=i*128+s][c] = fC[p] * sum_j PC[b][s][i][j] * xTbf[b][c][s*128+j]
__global__ __launch_bounds__(256) void kagg2(
    const unsigned short* __restrict__ PR, const unsigned short* __restrict__ PC,
    const float* __restrict__ x, const unsigned short* __restrict__ xbf,
    const unsigned short* __restrict__ xTbf,
    const float* __restrict__ FR, const float* __restrict__ FC,
    unsigned short* __restrict__ ySumR, unsigned short* __restrict__ ySumC)
{
    __shared__ __attribute__((aligned(16))) unsigned short sAttn[128 * 128];
    __shared__ __attribute__((aligned(16))) unsigned short sX[128 * 128];
    __shared__ float sF[128];
    const int tid = threadIdx.x;
    const int s = blockIdx.x, b = blockIdx.y, mode = blockIdx.z;
    const int lane = tid & 63, wv = tid >> 6;
    const int m0 = (wv >> 1) * 64, n0 = (wv & 1) * 64;   // m = c tile, n = i tile
    const int fr = lane & 15, fq = lane >> 4;

    // stage attention tile 128x128 once: linear LDS dest, inverse-swizzled src
    const unsigned short* At = (mode ? PC : PR) + ((size_t)(b * 128 + s)) * P_;
#pragma unroll
    for (int rep = 0; rep < 8; rep++) {
        const int idx = rep * 256 + tid;
        const int r = idx >> 4, sl = idx & 15;
        gl_lds16(&At[(size_t)r * 128 + (sl ^ (r & 7)) * 8], &sAttn[idx * 8]);
    }
    // stage per-row scale factors (contiguous 128 floats for this block)
    const float* Fsel = mode ? FC : FR;
    if (tid < 128) sF[tid] = Fsel[(((size_t)b * 128 + s) << 7) + tid];

    unsigned short* yS = mode ? ySumC : ySumR;
    const unsigned short* Xsrc = mode ? xTbf : xbf;

    for (int ct = 0; ct < 4; ct++) {
        if (Xsrc) {
            const unsigned short* Xs = &Xsrc[((size_t)(b * C_ + ct * 128)) * P_ + s * 128];
#pragma unroll
            for (int rep = 0; rep < 8; rep++) {
                const int idx = rep * 256 + tid;
                const int r = idx >> 4, sl = idx & 15;
                gl_lds16(&Xs[(size_t)r * P_ + (sl ^ (r & 7)) * 8], &sX[idx * 8]);
            }
        } else {
            const float* Xf = &x[((size_t)(b * C_ + ct * 128)) * P_ + s * 128];
#pragma unroll
            for (int rep = 0; rep < 16; rep++) {
                const int idx = rep * 256 + tid;
                const int jq = idx & 31, cc = idx >> 5;
                const float4 v = *(const float4*)&Xf[(size_t)cc * P_ + jq * 4];
                ushort4 u; u.x = f2bf(v.x); u.y = f2bf(v.y); u.z = f2bf(v.z); u.w = f2bf(v.w);
                *(ushort4*)&sX[SWZ128(cc, jq * 4)] = u;
            }
        }
        __syncthreads();

        f32x4 acc[4][4];
#pragma unroll
        for (int i = 0; i < 4; i++)
#pragma unroll
            for (int j = 0; j < 4; j++) acc[i][j] = (f32x4){0.f, 0.f, 0.f, 0.f};

#pragma unroll
        for (int kk = 0; kk < 128; kk += 32) {
            bf16x8 af[4], bfv[4];
#pragma unroll
            for (int t = 0; t < 4; t++) {
                const int rc = m0 + t * 16 + fr;
                af[t] = *(const bf16x8*)&sX[SWZ128(rc, kk + fq * 8)];
            }
#pragma unroll
            for (int t = 0; t < 4; t++) {
                const int ri = n0 + t * 16 + fr;
                bfv[t] = *(const bf16x8*)&sAttn[SWZ128(ri, kk + fq * 8)];
            }
#pragma unroll
            for (int i = 0; i < 4; i++)
#pragma unroll
                for (int j = 0; j < 4; j++)
                    acc[i][j] = MFMA16(af[i], bfv[j], acc[i][j]);
        }

        // epilogue: lane holds c = cg0 + ti*16 + {0..3}, i = n0 + tj*16 + fr
        const int cg0 = ct * 128 + m0 + fq * 4;
#pragma unroll
        for (int tj = 0; tj < 4; tj++) {
            const int i_g = n0 + tj * 16 + fr;
            const float fsc = sF[i_g];
            const size_t p = mode ? ((size_t)i_g * 128 + s) : ((size_t)s * 128 + i_g);
            unsigned short* rowp = yS + ((size_t)b * P_ + p) * 512;
#pragma unroll
            for (int ti = 0; ti < 4; ti++) {
                ushort4 u;
                u.x = f2bf(acc[ti][tj][0] * fsc); u.y = f2bf(acc[ti][tj][1] * fsc);
                u.z = f2bf(acc[ti][tj][2] * fsc); u.w = f2bf(acc[ti][tj][3] * fsc);
                *(ushort4*)&rowp[cg0 + ti * 16] = u;
            }
        }
        __syncthreads();   // all waves done reading sX before next ct overwrites it
    }
}

// ---------------------------------------------------------------------------
// Final GEMM, 256x256 tile, K=1024 concat, 2-deep pipelined — byte-identical
// to the r4 harness-verified best (136 us, VGPR 128, no spill).
__global__ __launch_bounds__(512, 2) void kfinal256(
    const unsigned short* __restrict__ Wvbf,
    const unsigned short* __restrict__ yR,
    const unsigned short* __restrict__ yC,
    float* __restrict__ outf,
    const float* __restrict__ addx,
    const float* __restrict__ gammap)
{
    __shared__ __attribute__((aligned(16))) unsigned short sM[2][256 * 64]; // Wv rows (m)
    __shared__ __attribute__((aligned(16))) unsigned short sP[2][256 * 64]; // ySum rows (p)
    const int tid = threadIdx.x;
    const int pbase = blockIdx.x * 256, mt = blockIdx.y, b = blockIdx.z;
    const int lane = tid & 63, wv = tid >> 6;
    const int m0w = (wv >> 2) * 128;   // 2 m-groups of 128
    const int p0w = (wv & 3) * 64;     // 4 p-groups of 64
    const int fr = lane & 15, fq = lane >> 4;

    f32x4 acc[4][8];
#pragma unroll
    for (int i = 0; i < 4; i++)
#pragma unroll
        for (int j = 0; j < 8; j++) acc[i][j] = (f32x4){0.f, 0.f, 0.f, 0.f};

    const unsigned short* Arow = Wvbf + (size_t)(mt * 256) * 512;
    const size_t brow = ((size_t)b * P_ + pbase) * 512;

#define FIN_STAGE(chunk, buf) {                                                 \
        const int kc_ = ((chunk) & 7) * 64;                                     \
        const unsigned short* Bp = ((chunk) < 8 ? yR : yC) + brow + kc_;        \
        const unsigned short* Ap = Arow + kc_;                                  \
        _Pragma("unroll")                                                       \
        for (int rep = 0; rep < 4; rep++) {                                     \
            const int idx = rep * 512 + tid;                                    \
            const int r_ = idx >> 3, kgs = (idx & 7) ^ (r_ & 7);                \
            gl_lds16(&Ap[(size_t)r_ * 512 + kgs * 8], &sM[buf][idx * 8]);       \
            gl_lds16(&Bp[(size_t)r_ * 512 + kgs * 8], &sP[buf][idx * 8]);       \
        } }

    FIN_STAGE(0, 0);
    int cur = 0;
    for (int chunk = 0; chunk < 16; ++chunk) {
        if (chunk < 15) {
            FIN_STAGE(chunk + 1, cur ^ 1);
            asm volatile("s_waitcnt vmcnt(8)" ::: "memory");   // chunk's 8 landed
        } else {
            asm volatile("s_waitcnt vmcnt(0)" ::: "memory");
        }
        __builtin_amdgcn_s_barrier();
#pragma unroll
        for (int kk = 0; kk < 64; kk += 32) {
            bf16x8 bp[4], am[8];
#pragma unroll
            for (int t = 0; t < 4; t++) bp[t] = *(const bf16x8*)&sP[cur][SWZ64(p0w + t * 16 + fr, kk + fq * 8)];
#pragma unroll
            for (int t = 0; t < 8; t++) am[t] = *(const bf16x8*)&sM[cur][SWZ64(m0w + t * 16 + fr, kk + fq * 8)];
            __builtin_amdgcn_s_setprio(1);
#pragma unroll
            for (int i = 0; i < 4; i++)
#pragma unroll
                for (int j = 0; j < 8; j++)
                    acc[i][j] = MFMA16(bp[i], am[j], acc[i][j]);
            __builtin_amdgcn_s_setprio(0);
        }
        if (chunk < 15) __builtin_amdgcn_s_barrier();  // readers done before re-stage
        cur ^= 1;
    }
#undef FIN_STAGE

    // epilogue: lane's 4 regs = 4 consecutive p; float4 RMW against addx
    const float g = gammap[0];
#pragma unroll
    for (int ti = 0; ti < 4; ti++) {
        const int p_g = pbase + p0w + ti * 16 + fq * 4;
#pragma unroll
        for (int tj = 0; tj < 8; tj++) {
            const int m_g = mt * 256 + m0w + tj * 16 + fr;
            const size_t off = ((size_t)(b * 512 + m_g)) * P_ + p_g;
            const float4 xa = *(const float4*)&addx[off];
            float4 o;
            o.x = fmaf(g, acc[ti][tj][0], xa.x);
            o.y = fmaf(g, acc[ti][tj][1], xa.y);
            o.z = fmaf(g, acc[ti][tj][2], xa.z);
            o.w = fmaf(g, acc[ti][tj][3], xa.w);
            *(float4*)&outf[off] = o;
        }
    }
}

// ---------------------------------------------------------------------------
extern "C" void kernel_launch(void* const* d_in, const int* in_sizes, int n_in,
                              void* d_out, int out_size, void* d_ws, size_t ws_size,
                              hipStream_t stream) {
    const float* x     = (const float*)d_in[0];
    const float* Wq    = (const float*)d_in[1];
    const float* Wk    = (const float*)d_in[2];
    const float* Wv    = (const float*)d_in[3];
    const float* gamma = (const float*)d_in[4];
    float* out = (float*)d_out;

    char* base = (char*)d_ws;
    unsigned short* Wqkbf = (unsigned short*)base;             base += 131072;      // 128x512
    unsigned short* Wvbf  = (unsigned short*)base;             base += 524288;      // 512x512
    unsigned short* xTbf  = (unsigned short*)base;             base += 67108864;    // [b][c][w][h]
    unsigned short* xbfT  = (unsigned short*)base;             base += 67108864;    // [b][p][c]
    unsigned short* qkP   = (unsigned short*)base;             base += 16777216;    // [b][p][mk]
    char*           freeRC = base;                             base += 67108864;    // scratch: ySumC lives here
    unsigned short* PR    = (unsigned short*)base;             base += 16777216;    // [b][h][w][j] bf16 (unnormalized)
    unsigned short* PC    = (unsigned short*)base;             base += 16777216;    // [b][w][h][j]
    unsigned short* ySumR = (unsigned short*)base;             base += 67108864;    // [b][p][c]
    float*          MR    = (float*)base;                      base += 262144;      // [b][h][w]
    float*          SR    = (float*)base;                      base += 262144;
    float*          MC    = (float*)base;                      base += 262144;      // [b][w][h]
    float*          SC    = (float*)base;                      base += 262144;
    float*          FR    = (float*)base;                      base += 262144;
    float*          FC    = (float*)base;                      base += 262144;
    unsigned short* ySumC = (unsigned short*)freeRC;
    // xbf [b][c][p] bf16 straight-cast copy (64 MiB) — only if workspace allows
    const size_t used = (size_t)(base - (char*)d_ws);
    unsigned short* xbf = nullptr;
    if (ws_size >= used + 67108864) { xbf = (unsigned short*)base; base += 67108864; }

    kwconv<<<320, 256, 0, stream>>>(Wq, Wk, Wv, Wqkbf, Wvbf);
    kprep1<<<dim3(16, 2048), 256, 0, stream>>>(x, xTbf, xbf);
    // c<->p transpose; reads bf16 xbf when available (half the read traffic)
    kprep2<<<dim3(512, 16, 4), 256, 0, stream>>>(x, xbf, xbfT);
    // qk[b][p][mk] = Wqk @ x
    kgemmqk<<<dim3(128, 1, 4), 256, 0, stream>>>(Wqkbf, xbfT, qkP);
    // row (eW) + col (eH, diag-masked) logits -> unnormalized P + (m,s) scalars
    klogitsP<<<dim3(128, 4, 2), 256, 0, stream>>>(qkP, PR, PC, MR, SR, MC, SC);
    // joint-softmax scale factors
    kcomb<<<256, 256, 0, stream>>>(MR, SR, MC, SC, FR, FC);
    // fused row+col aggregation (scale folded into epilogue) -> ySumR / ySumC
    kagg2<<<dim3(128, 4, 2), 256, 0, stream>>>(PR, PC, x, xbf, xTbf, FR, FC, ySumR, ySumC);
    // out = gamma * Wv @ [ySumR | ySumC] + x, 256^2 double-buffered (r4-exact)
    kfinal256<<<dim3(64, 2, 4), 512, 0, stream>>>(Wvbf, ySumR, ySumC, out, x, gamma);
}